// Round 8
// baseline (1583.933 us; speedup 1.0000x reference)
//
#include <hip/hip_runtime.h>
#include <hip/hip_bf16.h>

// Problem constants
#define VV 3
#define NN 8192
#define HH 128
#define ADIM 64
#define FOUT 128

typedef short bf16x8 __attribute__((ext_vector_type(8)));
typedef float f32x4 __attribute__((ext_vector_type(4)));
typedef unsigned char uchar;

__device__ __forceinline__ float bf2f(ushort u) {
    union { unsigned int i; float f; } x; x.i = ((unsigned int)u) << 16; return x.f;
}
__device__ __forceinline__ ushort f2bf(float f) {
    union { float f; unsigned int i; } x; x.f = f;
    unsigned int r = (x.i + 0x7FFFu + ((x.i >> 16) & 1u)) >> 16;
    return (ushort)r;
}
__device__ __forceinline__ void async_cp16(const void* g, void* l) {
    __builtin_amdgcn_global_load_lds(
        (const __attribute__((address_space(1))) void*)g,
        (__attribute__((address_space(3))) void*)l, 16, 0, 0);
}

// ---------------------------------------------------------------------------
// zero a small region (summ floats + deg ints); ws is poisoned every call
__global__ void zero_k(float* p, int n) {
    int i = blockIdx.x * blockDim.x + threadIdx.x;
    if (i < n) p[i] = 0.0f;
}

// ---------------------------------------------------------------------------
// pack adjacency to 1-bit in GEMM staging order + degree atomics.
// Layout: chunk (z*64+mt)*128 + kc is 1 KB = [row 0..127][8 bytes]; byte b of
// row r covers cols kc*64 + b*8 .. +7, bit j = col +j. Block (ks,mt,z) covers
// rows mt*128..+127, kc = ks*64..+63 -> contiguous 64 KB write.
__global__ __launch_bounds__(256) void pack_k(const int* __restrict__ adj,
                                              uchar* __restrict__ abits,
                                              int* __restrict__ deg) {
    const int t = threadIdx.x;
    const int r = t >> 1, half = t & 1;
    const int ks = blockIdx.x, mt = blockIdx.y, z = blockIdx.z;
    const int n = mt * 128 + r;
    const long rowoff = ((long)z * NN + n) * NN;
    uint* dst = (uint*)(abits + (((long)z * 64 + mt) * 128 << 10));
    int cnt = 0;
    for (int kc = ks * 64; kc < ks * 64 + 64; kc++) {
        const int colbase = kc * 64 + half * 32;
        uint wbits = 0;
        #pragma unroll
        for (int i = 0; i < 8; i++) {
            const int c0 = colbase + i * 4;
            const int4 v = *(const int4*)(adj + rowoff + c0);
            uint b0 = (v.x != 0 || c0 + 0 == n) ? 1u : 0u;
            uint b1 = (v.y != 0 || c0 + 1 == n) ? 1u : 0u;
            uint b2 = (v.z != 0 || c0 + 2 == n) ? 1u : 0u;
            uint b3 = (v.w != 0 || c0 + 3 == n) ? 1u : 0u;
            wbits |= (b0 | (b1 << 1) | (b2 << 2) | (b3 << 3)) << (i * 4);
        }
        cnt += __popc(wbits);
        dst[kc * 256 + r * 2 + half] = wbits;
    }
    cnt += __shfl_xor(cnt, 1);
    if (half == 0) atomicAdd(&deg[z * NN + n], cnt);
}

// ---------------------------------------------------------------------------
__global__ void dinv_k(const int* __restrict__ deg, float* __restrict__ dinv) {
    int i = blockIdx.x * blockDim.x + threadIdx.x;
    if (i < VV * NN) dinv[i] = rsqrtf((float)deg[i]);
}

// ---------------------------------------------------------------------------
// transpose (R x C) -> (C x R) per z, optional per-input-row scale (dinv).
// INF32: input is float32 (weights); else input is bf16 ushort (ws buffers).
template<int INF32>
__global__ void transpose_scale_k(const void* __restrict__ in_, ushort* __restrict__ out,
                                  int R, int C, const float* __restrict__ scale, int scale_z) {
    __shared__ ushort tile[32][33];
    const long zo = (long)blockIdx.z * R * C;
    const int c0 = blockIdx.x * 32, r0 = blockIdx.y * 32;
    const int t = threadIdx.x;
    #pragma unroll
    for (int p = 0; p < 4; p++) {
        int e = p * 256 + t; int row = e >> 5, col = e & 31;
        long idx = zo + (long)(r0 + row) * C + c0 + col;
        float x = INF32 ? ((const float*)in_)[idx] : bf2f(((const ushort*)in_)[idx]);
        if (scale) x *= scale[(long)blockIdx.z * scale_z + r0 + row];
        tile[row][col] = f2bf(x);
    }
    __syncthreads();
    #pragma unroll
    for (int p = 0; p < 4; p++) {
        int e = p * 256 + t; int row = e >> 5, col = e & 31;   // row indexes C-dim now
        out[zo + (long)(c0 + row) * R + r0 + col] = tile[col][row];
    }
}

// ---------------------------------------------------------------------------
// Adjacency GEMM, full-K, fused epilogue: h = relu(dinv_i * (A@Bt^T) + bias).
// 64x128 tile, 256 threads (4 waves: 2x2 over 32-row x 64-col sub-tiles),
// BK=64. A = 1-bit (pack_k layout) expanded in-register; B = bf16 staged
// with XOR swizzle via global_load_lds.
template<int WRITE_F32>
__global__ __launch_bounds__(256) void gemm_adj_k(
    const uchar* __restrict__ abits,
    const ushort* __restrict__ Bt,      // V x 128 x N bf16 (K-contiguous)
    const float* __restrict__ dinv,     // V x N
    const float* __restrict__ bias,     // V x H f32
    ushort* __restrict__ hout,          // V x N x H bf16
    float* __restrict__ fout)           // V x N x H f32 (if WRITE_F32)
{
    __shared__ __align__(16) uchar As[512];
    __shared__ __align__(16) ushort Bs[128 * 64];
    const int tid = threadIdx.x, lane = tid & 63, w = tid >> 6;
    const int wrow = w >> 1, wcol = w & 1;
    const int mt = blockIdx.x, z = blockIdx.y;      // mt: 64-row tile
    const int m0 = mt * 64;
    const uchar* Achunks = abits + (((long)z * 64 + (mt >> 1)) * 128 << 10);
    const int arow_off = (mt & 1) * 512;            // 64 rows x 8 B within chunk
    const ushort* Bv = Bt + (long)z * 128 * NN;
    f32x4 acc[2][4] = {};

    int srow[4], slcb[4];
    #pragma unroll
    for (int p = 0; p < 4; p++) {
        int slot = p * 256 + tid;                    // 0..1023
        srow[p] = slot >> 3;                         // B row (C column)
        slcb[p] = (slot & 7) ^ (srow[p] & 7);        // XOR-swizzled 16B block
    }

    for (int kc = 0; kc < 128; kc++) {
        if (tid < 32)
            async_cp16(Achunks + ((long)kc << 10) + arow_off + tid * 16, As + tid * 16);
        const int k0 = kc * 64;
        #pragma unroll
        for (int p = 0; p < 4; p++) {
            const int slot = p * 256 + tid;
            async_cp16(Bv + (long)srow[p] * NN + k0 + slcb[p] * 8, Bs + slot * 8);
        }
        __syncthreads();
        const int q = lane >> 4;
        uint2 bitsarr[2];
        #pragma unroll
        for (int mi = 0; mi < 2; mi++)
            bitsarr[mi] = *(const uint2*)&As[(wrow * 32 + mi * 16 + (lane & 15)) * 8];
        #pragma unroll
        for (int s = 0; s < 2; s++) {
            bf16x8 bb[4];
            const int ca = s * 4 + q;
            #pragma unroll
            for (int ni = 0; ni < 4; ni++) {
                int brow = wcol * 64 + ni * 16 + (lane & 15);
                bb[ni] = *(const bf16x8*)&Bs[brow * 64 + ((ca ^ (brow & 7)) * 8)];
            }
            #pragma unroll
            for (int mi = 0; mi < 2; mi++) {
                const uint wsel = s ? bitsarr[mi].y : bitsarr[mi].x;
                const uint b = (wsel >> (q * 8)) & 0xffu;
                union { uint4 u; bf16x8 v; } cvt;
                cvt.u.x = ((b     ) & 1u) * 0x00003F80u | ((b >> 1) & 1u) * 0x3F800000u;
                cvt.u.y = ((b >> 2) & 1u) * 0x00003F80u | ((b >> 3) & 1u) * 0x3F800000u;
                cvt.u.z = ((b >> 4) & 1u) * 0x00003F80u | ((b >> 5) & 1u) * 0x3F800000u;
                cvt.u.w = ((b >> 6) & 1u) * 0x00003F80u | ((b >> 7) & 1u) * 0x3F800000u;
                #pragma unroll
                for (int ni = 0; ni < 4; ni++)
                    acc[mi][ni] = __builtin_amdgcn_mfma_f32_16x16x32_bf16(cvt.v, bb[ni], acc[mi][ni], 0, 0, 0);
            }
        }
        __syncthreads();
    }

    const long zo = (long)z * NN * HH;
    #pragma unroll
    for (int mi = 0; mi < 2; mi++) {
        int rbase = m0 + wrow * 32 + mi * 16 + ((lane >> 4) << 2);
        #pragma unroll
        for (int ni = 0; ni < 4; ni++) {
            int col = wcol * 64 + ni * 16 + (lane & 15);
            float bcol = bias[z * HH + col];
            #pragma unroll
            for (int r = 0; r < 4; r++) {
                int grow = rbase + r;
                float v = fmaxf(acc[mi][ni][r] * dinv[(long)z * NN + grow] + bcol, 0.0f);
                hout[zo + (long)grow * HH + col] = f2bf(v);
                if (WRITE_F32) fout[zo + (long)grow * HH + col] = v;
            }
        }
    }
}

// ---------------------------------------------------------------------------
// Generic 128x128-tile MFMA GEMM for the small GEMMs.
// AMODE 1: A = bf16 row-major (ws), lda given
// AMODE 2: A = h (V,N,H) bf16 (ws), K runs over v*H+h', scaled by attn[v]
// EPI 1: dinv[row]*acc ; EPI 2: relu(acc + bias[col]) ; EPI 3: acc + bias[col]
template<int AMODE, int EPI, int OUTF32>
__global__ __launch_bounds__(256) void gemm_k(
    const void* __restrict__ Aany, long a_zs, int lda,
    const ushort* __restrict__ Bt, long b_zs, int ldb,
    void* __restrict__ Cc, long c_zs, int ldc,
    int Ktot,
    const float* __restrict__ dinv, int dinv_zs,
    const float* __restrict__ bias, int bias_zs,
    const float* __restrict__ attnp)
{
    __shared__ __align__(16) ushort As[128][40];
    __shared__ __align__(16) ushort Bs[128][40];
    const int tid = threadIdx.x;
    const int bx = blockIdx.x, by = blockIdx.y, z = blockIdx.z;
    const int m0 = by * 128, n0 = bx * 128;
    const int lane = tid & 63, w = tid >> 6, wr = w >> 1, wcq = w & 1;
    f32x4 acc[4][4] = {};
    float att0 = 0.f, att1 = 0.f, att2 = 0.f;
    if (AMODE == 2) { att0 = attnp[0]; att1 = attnp[1]; att2 = attnp[2]; }
    const ushort* Ab = (const ushort*)Aany + (long)z * (AMODE == 1 ? a_zs : 0);
    const ushort* Btz = Bt + (long)z * b_zs;

    for (int k0 = 0; k0 < Ktot; k0 += 32) {
        if (AMODE == 1) {
            #pragma unroll
            for (int p = 0; p < 2; p++) {
                int c = p * 256 + tid;
                int row = c >> 2, q = c & 3;
                *(int4*)&As[row][q * 8] = *(const int4*)(Ab + (long)(m0 + row) * lda + k0 + q * 8);
            }
        } else {
            #pragma unroll
            for (int p = 0; p < 2; p++) {
                int c = p * 256 + tid;
                int row = c >> 2, q = c & 3;
                int kk = k0 + q * 8;
                int v = kk >> 7, ko = kk & 127;
                int4 raw = *(const int4*)((const ushort*)Aany + (long)v * a_zs + (long)(m0 + row) * HH + ko);
                float sc = (v == 0) ? att0 : (v == 1 ? att1 : att2);
                __align__(16) ushort us[8];
                *(int4*)us = raw;
                #pragma unroll
                for (int e = 0; e < 8; e++) us[e] = f2bf(bf2f(us[e]) * sc);
                *(int4*)&As[row][q * 8] = *(int4*)us;
            }
        }
        #pragma unroll
        for (int p = 0; p < 2; p++) {
            int c = p * 256 + tid;
            int n = c >> 2, q = c & 3;
            *(int4*)&Bs[n][q * 8] = *(const int4*)(Btz + (long)(n0 + n) * ldb + k0 + q * 8);
        }
        __syncthreads();
        bf16x8 af[4], bfr[4];
        #pragma unroll
        for (int mi = 0; mi < 4; mi++)
            af[mi] = *(const bf16x8*)&As[wr * 64 + mi * 16 + (lane & 15)][(lane >> 4) * 8];
        #pragma unroll
        for (int ni = 0; ni < 4; ni++)
            bfr[ni] = *(const bf16x8*)&Bs[wcq * 64 + ni * 16 + (lane & 15)][(lane >> 4) * 8];
        #pragma unroll
        for (int mi = 0; mi < 4; mi++)
            #pragma unroll
            for (int ni = 0; ni < 4; ni++)
                acc[mi][ni] = __builtin_amdgcn_mfma_f32_16x16x32_bf16(af[mi], bfr[ni], acc[mi][ni], 0, 0, 0);
        __syncthreads();
    }

    #pragma unroll
    for (int mi = 0; mi < 4; mi++) {
        int rbase = m0 + wr * 64 + mi * 16 + ((lane >> 4) << 2);
        #pragma unroll
        for (int ni = 0; ni < 4; ni++) {
            int col = n0 + wcq * 64 + ni * 16 + (lane & 15);
            #pragma unroll
            for (int r = 0; r < 4; r++) {
                int grow = rbase + r;
                float vv = acc[mi][ni][r];
                if (EPI == 1) vv *= dinv[(long)z * dinv_zs + grow];
                if (EPI == 2 || EPI == 3) vv += bias[col];
                if (EPI == 2) vv = fmaxf(vv, 0.0f);
                if (OUTF32) ((float*)Cc + (long)z * c_zs)[(long)grow * ldc + col] = vv;
                else        ((ushort*)Cc + (long)z * c_zs)[(long)grow * ldc + col] = f2bf(vv);
            }
        }
    }
}

// ---------------------------------------------------------------------------
// column sums of h2 (bf16 ws) into summ[v*H+col]
__global__ __launch_bounds__(256) void colsum_k(const ushort* __restrict__ h2,
                                                float* __restrict__ summ) {
    const int rowbase = blockIdx.x * 64;
    const int z = rowbase >> 13;
    const int col = threadIdx.x & 127, half = threadIdx.x >> 7;
    float s = 0.0f;
    for (int r = half; r < 64; r += 2) s += bf2f(h2[(long)(rowbase + r) * HH + col]);
    atomicAdd(&summ[z * HH + col], s);
}

// ---------------------------------------------------------------------------
// attention: summ(sum)/N -> tanh(@Wa1+ba1)@Wa2+ba2 -> softmax over V
__global__ __launch_bounds__(256) void attn_k(const float* __restrict__ summ,
                                              const float* __restrict__ Wa1,
                                              const float* __restrict__ ba1,
                                              const float* __restrict__ Wa2,
                                              const float* __restrict__ ba2,
                                              float* __restrict__ attnws,
                                              float* __restrict__ out_attn) {
    __shared__ float sc[VV];
    const int tid = threadIdx.x;
    if (tid < VV * 64) {
        const int v = tid >> 6, a = tid & 63;
        float s = ba1[a];
        const float invN = 1.0f / (float)NN;
        #pragma unroll 4
        for (int h = 0; h < HH; h++) s += summ[v * HH + h] * invN * Wa1[h * ADIM + a];
        float p = tanhf(s) * Wa2[a];
        for (int off = 32; off; off >>= 1) p += __shfl_down(p, off);
        if (a == 0) sc[v] = p + ba2[0];
    }
    __syncthreads();
    if (tid == 0) {
        float m = fmaxf(sc[0], fmaxf(sc[1], sc[2]));
        float e0 = expf(sc[0] - m), e1 = expf(sc[1] - m), e2 = expf(sc[2] - m);
        float inv = 1.0f / (e0 + e1 + e2);
        attnws[0] = e0 * inv; attnws[1] = e1 * inv; attnws[2] = e2 * inv;
        out_attn[0] = e0 * inv; out_attn[1] = e1 * inv; out_attn[2] = e2 * inv;
    }
}

// ---------------------------------------------------------------------------
extern "C" void kernel_launch(void* const* d_in, const int* in_sizes, int n_in,
                              void* d_out, int out_size, void* d_ws, size_t ws_size,
                              hipStream_t stream) {
    const int*   adj = (const int*)d_in[0];
    const float* W1  = (const float*)d_in[1];
    const float* b1  = (const float*)d_in[2];
    const float* W2  = (const float*)d_in[3];
    const float* b2  = (const float*)d_in[4];
    const float* Wa1 = (const float*)d_in[5];
    const float* ba1 = (const float*)d_in[6];
    const float* Wa2 = (const float*)d_in[7];
    const float* ba2 = (const float*)d_in[8];
    const float* Wf1 = (const float*)d_in[9];
    const float* bf1 = (const float*)d_in[10];
    const float* Wf2 = (const float*)d_in[11];
    const float* bf2v = (const float*)d_in[12];

    float* out = (float*)d_out;
    float* out_fused = out;                                  // (N, FOUT)
    float* out_attn  = out + (long)NN * FOUT;                // (V,)
    float* out_h     = out + (long)NN * FOUT + VV;           // (V,N,H)

    char* wsb = (char*)d_ws;
    const long SZ_DINV  = (long)VV * NN * 4;                 // 98304
    const long SZ_ABITS = (long)VV * 64 * 128 * 1024;        // 25165824
    const long SZ_W1T   = (long)VV * HH * NN * 2;            // 6291456
    const long SZ_W2T   = (long)VV * HH * HH * 2;            // 98304
    const long SZ_WF1T  = 256L * 384 * 2;                    // 196608
    const long SZ_WF2T  = 128L * 256 * 2;                    // 65536
    const long SZ_VNH   = (long)VV * NN * HH * 2;            // 6291456
    const long SZ_G     = (long)NN * 256 * 2;                // 4194304
    long off = 0;
    float*  dinv  = (float*)(wsb + off);  off += SZ_DINV;
    uchar*  abits = (uchar*)(wsb + off);  off += SZ_ABITS;
    ushort* w1t   = (ushort*)(wsb + off); off += SZ_W1T;
    ushort* w2t   = (ushort*)(wsb + off); off += SZ_W2T;
    ushort* wf1t  = (ushort*)(wsb + off); off += SZ_WF1T;
    ushort* wf2t  = (ushort*)(wsb + off); off += SZ_WF2T;
    ushort* h1    = (ushort*)(wsb + off); off += SZ_VNH;
    ushort* tbuf  = (ushort*)(wsb + off); off += SZ_VNH;
    ushort* tT    = (ushort*)(wsb + off); off += SZ_VNH;
    ushort* h2    = (ushort*)(wsb + off); off += SZ_VNH;
    ushort* G     = (ushort*)(wsb + off); off += SZ_G;
    float*  summ  = (float*)(wsb + off);  off += 1600;       // 400 floats
    float*  attnw = summ + 384;                              // inside zeroed region
    int*    deg   = (int*)(wsb + off);    off += (long)VV * NN * 4;

    const long VNH = (long)NN * HH;

    // 1) zero summ (400 floats) + deg (VV*NN ints), contiguous
    zero_k<<<98, 256, 0, stream>>>(summ, 400 + VV * NN);
    // 2) bit-pack adjacency (staging-order layout) + degree atomics
    pack_k<<<dim3(2, 64, VV), 256, 0, stream>>>(adj, abits, deg);
    // 3) dinv = rsqrt(deg)
    dinv_k<<<96, 256, 0, stream>>>(deg, dinv);
    // 4) weight transposes (B operands staged as (Ncols x K) row-major, bf16)
    transpose_scale_k<1><<<dim3(4, 256, VV), 256, 0, stream>>>(W1, w1t, NN, HH, dinv, NN);
    transpose_scale_k<1><<<dim3(4, 4, VV), 256, 0, stream>>>(W2, w2t, HH, HH, nullptr, 0);
    transpose_scale_k<1><<<dim3(8, 12, 1), 256, 0, stream>>>(Wf1, wf1t, 384, 256, nullptr, 0);
    transpose_scale_k<1><<<dim3(4, 8, 1), 256, 0, stream>>>(Wf2, wf2t, 256, 128, nullptr, 0);
    // 5) h1 = relu(dinv_i * (A @ dinv_j*W1) + b1)   (full-K, fused epilogue)
    gemm_adj_k<0><<<dim3(128, VV), 256, 0, stream>>>(abits, w1t, dinv, b1, h1, nullptr);
    // 6) t = dinv_k * (h1 @ W2)
    gemm_k<1, 1, 0><<<dim3(1, 64, VV), 256, 0, stream>>>(h1, VNH, HH, w2t, (long)HH * HH, HH,
                                                         tbuf, VNH, HH, HH, dinv, NN, nullptr, 0, nullptr);
    // 7) tT[v][n][k] = t[v][k][n]
    transpose_scale_k<0><<<dim3(4, 256, VV), 256, 0, stream>>>(tbuf, tT, NN, HH, nullptr, 0);
    // 8) h2 = relu(dinv_i * (A @ t) + b2) -> bf16 ws + f32 out  (fused)
    gemm_adj_k<1><<<dim3(128, VV), 256, 0, stream>>>(abits, tT, dinv, b2, h2, out_h);
    // 9) column sums for attention
    colsum_k<<<(VV * NN) / 64, 256, 0, stream>>>(h2, summ);
    // 10) attention weights
    attn_k<<<1, 256, 0, stream>>>(summ, Wa1, ba1, Wa2, ba2, attnw, out_attn);
    // 11) G = relu([attn_v*h_v] @ Wf1 + bf1)   (M=8192, K=384, Ncols=256)
    gemm_k<2, 2, 0><<<dim3(2, 64, 1), 256, 0, stream>>>(h2, VNH, HH, wf1t, 0, 384,
                                                        G, 0, 256, 384, nullptr, 0, bf1, 0, attnw);
    // 12) fused = G @ Wf2 + bf2                (M=8192, K=256, Ncols=128)
    gemm_k<1, 3, 1><<<dim3(1, 64, 1), 256, 0, stream>>>(G, 0, 256, wf2t, 0, 256,
                                                        out_fused, 0, FOUT, 256, nullptr, 0, bf2v, 0, nullptr);
}

// Round 9
// 1266.647 us; speedup vs baseline: 1.2505x; 1.2505x over previous
//
#include <hip/hip_runtime.h>
#include <hip/hip_bf16.h>

// Problem constants
#define VV 3
#define NN 8192
#define HH 128
#define ADIM 64
#define FOUT 128
#define KSPLIT 4

typedef short bf16x8 __attribute__((ext_vector_type(8)));
typedef float f32x4 __attribute__((ext_vector_type(4)));
typedef unsigned char uchar;

__device__ __forceinline__ float bf2f(ushort u) {
    union { unsigned int i; float f; } x; x.i = ((unsigned int)u) << 16; return x.f;
}
__device__ __forceinline__ ushort f2bf(float f) {
    union { float f; unsigned int i; } x; x.f = f;
    unsigned int r = (x.i + 0x7FFFu + ((x.i >> 16) & 1u)) >> 16;
    return (ushort)r;
}
__device__ __forceinline__ void async_cp16(const void* g, void* l) {
    __builtin_amdgcn_global_load_lds(
        (const __attribute__((address_space(1))) void*)g,
        (__attribute__((address_space(3))) void*)l, 16, 0, 0);
}

// ---------------------------------------------------------------------------
// zero a small float region (summ + attn scratch)
__global__ void zero_k(float* p, int n) {
    int i = blockIdx.x * blockDim.x + threadIdx.x;
    if (i < n) p[i] = 0.0f;
}

// ---------------------------------------------------------------------------
// pack adjacency to 1-bit tiled layout, fully-coalesced reads (R4 pattern:
// wave per row, lane*4 consecutive cols, 1 KB per wave instruction).
// Bits assembled via shuffle tree (nibble->byte->u16->u32), staged in LDS,
// written as 8 B per chunk-row. dinv fused via wave reduction.
// Chunk layout: chunk (z*64+mt)*128 + kc is 1 KB = [row r: 8 B at r*8];
// byte b of row r covers cols kc*64 + b*8..+7, bit j = col +j.
__global__ __launch_bounds__(256) void pack_k(const int* __restrict__ adj,
                                              uchar* __restrict__ abits,
                                              float* __restrict__ dinv) {
    __shared__ uint rowbuf[4][256];                // per-wave 1 KB row image
    const int t = threadIdx.x, w = t >> 6, lane = t & 63;
    const long rowg = (long)blockIdx.x * 4 + w;    // z*N + n
    const int n = (int)(rowg & (NN - 1));
    const int z = (int)(rowg >> 13);
    const int mt = n >> 7, r = n & 127;
    const int* row = adj + rowg * NN;
    int cnt = 0;
    for (int it = 0; it < 32; it++) {
        const int c0 = it * 256 + lane * 4;
        const int4 v = *(const int4*)(row + c0);
        uint nib = (uint)(v.x != 0 || c0 + 0 == n)
                 | ((uint)(v.y != 0 || c0 + 1 == n) << 1)
                 | ((uint)(v.z != 0 || c0 + 2 == n) << 2)
                 | ((uint)(v.w != 0 || c0 + 3 == n) << 3);
        cnt += __popc(nib);
        uint x = nib << ((lane & 1) * 4);
        x |= __shfl_xor(x, 1);
        x <<= ((lane >> 1) & 1) * 8;
        x |= __shfl_xor(x, 2);
        x <<= ((lane >> 2) & 1) * 16;
        x |= __shfl_xor(x, 4);                     // all 8 lanes: u32 for cols base..+31
        if ((lane & 7) == 0) rowbuf[w][it * 8 + (lane >> 3)] = x;
    }
    for (int off = 32; off; off >>= 1) cnt += __shfl_down(cnt, off);
    if (lane == 0) dinv[rowg] = rsqrtf((float)cnt);
    __syncthreads();
    uint2* dstbase = (uint2*)(abits + (((long)z * 64 + mt) * 128 << 10) + r * 8);
    #pragma unroll
    for (int ph = 0; ph < 2; ph++) {
        const int kc = ph * 64 + lane;
        dstbase[(long)kc * 128] = *(const uint2*)&rowbuf[w][kc * 2];
    }
}

// ---------------------------------------------------------------------------
// transpose (R x C) -> (C x R) per z, optional per-input-row scale (dinv).
// INF32: input is float32 (weights); else input is bf16 ushort (ws buffers).
template<int INF32>
__global__ void transpose_scale_k(const void* __restrict__ in_, ushort* __restrict__ out,
                                  int R, int C, const float* __restrict__ scale, int scale_z) {
    __shared__ ushort tile[32][33];
    const long zo = (long)blockIdx.z * R * C;
    const int c0 = blockIdx.x * 32, r0 = blockIdx.y * 32;
    const int t = threadIdx.x;
    #pragma unroll
    for (int p = 0; p < 4; p++) {
        int e = p * 256 + t; int row = e >> 5, col = e & 31;
        long idx = zo + (long)(r0 + row) * C + c0 + col;
        float x = INF32 ? ((const float*)in_)[idx] : bf2f(((const ushort*)in_)[idx]);
        if (scale) x *= scale[(long)blockIdx.z * scale_z + r0 + row];
        tile[row][col] = f2bf(x);
    }
    __syncthreads();
    #pragma unroll
    for (int p = 0; p < 4; p++) {
        int e = p * 256 + t; int row = e >> 5, col = e & 31;   // row indexes C-dim now
        out[zo + (long)(c0 + row) * R + r0 + col] = tile[col][row];
    }
}

// ---------------------------------------------------------------------------
// Adjacency GEMM with 1-bit A (round-6 validated): Cpart[ks][v] = A(bits)@Bt^T.
// 128x128 tile, BK=64, split-K=KSPLIT, 256 threads (4 waves, 64x64 each).
// A-chunk = 1 KB/iter via one global_load_lds by wave 0; fragments expand
// bits -> bf16 {0,1} in-register. B staged XOR-swizzled via global_load_lds.
__global__ __launch_bounds__(256) void gemm_adj_k(
    const uchar* __restrict__ abits,    // tiled bits, see pack_k
    const ushort* __restrict__ Bt,      // V x 128 x N bf16 (K-contiguous)
    float* __restrict__ Cpart)          // KSPLIT x V x N x 128 f32
{
    __shared__ __align__(16) uchar As[1024];
    __shared__ __align__(16) ushort Bs[128 * 64];
    const int tid = threadIdx.x, lane = tid & 63, w = tid >> 6;
    const int wr = w >> 1, wc = w & 1;
    const int ks = blockIdx.x, mt = blockIdx.y, z = blockIdx.z;
    const int m0 = mt * 128;
    const int kbeg = ks * (NN / KSPLIT);
    const uchar* Atile = abits + (((long)z * 64 + mt) * 128 << 10);
    const ushort* Bv = Bt + (long)z * 128 * NN;
    f32x4 acc[4][4] = {};

    int srow[4], slcb[4];
    #pragma unroll
    for (int p = 0; p < 4; p++) {
        int slot = (w * 4 + p) * 64 + lane;       // 0..1023, wave-contiguous
        srow[p] = slot >> 3;                       // B row (C column)
        slcb[p] = (slot & 7) ^ (srow[p] & 7);      // XOR-swizzled 16B col-block
    }

    for (int k0 = kbeg; k0 < kbeg + NN / KSPLIT; k0 += 64) {
        if (w == 0)
            async_cp16(Atile + ((long)(k0 >> 6) << 10) + lane * 16, As + lane * 16);
        #pragma unroll
        for (int p = 0; p < 4; p++) {
            const int slot = (w * 4 + p) * 64 + lane;
            async_cp16(Bv + (long)srow[p] * NN + k0 + slcb[p] * 8, Bs + slot * 8);
        }
        __syncthreads();
        const int q = lane >> 4;
        #pragma unroll
        for (int s = 0; s < 2; s++) {
            bf16x8 af[4], bb[4];
            #pragma unroll
            for (int mi = 0; mi < 4; mi++) {
                const int r = wr * 64 + mi * 16 + (lane & 15);
                const uint b = As[r * 8 + s * 4 + q];
                union { uint4 u; bf16x8 v; } cvt;
                cvt.u.x = ((b     ) & 1u) * 0x00003F80u | ((b >> 1) & 1u) * 0x3F800000u;
                cvt.u.y = ((b >> 2) & 1u) * 0x00003F80u | ((b >> 3) & 1u) * 0x3F800000u;
                cvt.u.z = ((b >> 4) & 1u) * 0x00003F80u | ((b >> 5) & 1u) * 0x3F800000u;
                cvt.u.w = ((b >> 6) & 1u) * 0x00003F80u | ((b >> 7) & 1u) * 0x3F800000u;
                af[mi] = cvt.v;
            }
            const int ca = s * 4 + q;
            #pragma unroll
            for (int ni = 0; ni < 4; ni++) {
                int rr = wc * 64 + ni * 16 + (lane & 15);
                bb[ni] = *(const bf16x8*)&Bs[rr * 64 + ((ca ^ (rr & 7)) * 8)];
            }
            #pragma unroll
            for (int mi = 0; mi < 4; mi++)
                #pragma unroll
                for (int ni = 0; ni < 4; ni++)
                    acc[mi][ni] = __builtin_amdgcn_mfma_f32_16x16x32_bf16(af[mi], bb[ni], acc[mi][ni], 0, 0, 0);
        }
        __syncthreads();
    }

    float* C = Cpart + ((long)ks * VV + z) * ((long)NN * HH);
    #pragma unroll
    for (int mi = 0; mi < 4; mi++) {
        int rbase = m0 + wr * 64 + mi * 16 + ((lane >> 4) << 2);
        #pragma unroll
        for (int ni = 0; ni < 4; ni++) {
            int col = wc * 64 + ni * 16 + (lane & 15);
            #pragma unroll
            for (int r = 0; r < 4; r++)
                C[(long)(rbase + r) * HH + col] = acc[mi][ni][r];
        }
    }
}

// ---------------------------------------------------------------------------
// reduce KSPLIT partials + epilogue: h = relu(dinv[row]*sum + bias[v][col]),
// write bf16 (ws); WRITE_F32: also write f32 to fout (the h output region).
template<int WRITE_F32>
__global__ __launch_bounds__(256) void reduce_k(const float* __restrict__ P,
                                                const float* __restrict__ dinv,
                                                const float* __restrict__ bias,
                                                ushort* __restrict__ hout,
                                                float* __restrict__ fout) {
    const long e = ((long)blockIdx.x * 256 + threadIdx.x) * 4;
    const int v = (int)(e >> 20);                  // N*H = 2^20 per view
    const int n = (int)((e >> 7) & (NN - 1));
    const int col = (int)(e & 127);
    const long S = (long)VV * NN * HH;
    const float4 s0 = *(const float4*)(P + e);
    const float4 s1 = *(const float4*)(P + S + e);
    const float4 s2 = *(const float4*)(P + 2 * S + e);
    const float4 s3 = *(const float4*)(P + 3 * S + e);
    const float d = dinv[v * NN + n];
    const float r0 = fmaxf((s0.x + s1.x + s2.x + s3.x) * d + bias[v * HH + col + 0], 0.f);
    const float r1 = fmaxf((s0.y + s1.y + s2.y + s3.y) * d + bias[v * HH + col + 1], 0.f);
    const float r2 = fmaxf((s0.z + s1.z + s2.z + s3.z) * d + bias[v * HH + col + 2], 0.f);
    const float r3 = fmaxf((s0.w + s1.w + s2.w + s3.w) * d + bias[v * HH + col + 3], 0.f);
    ushort4 o; o.x = f2bf(r0); o.y = f2bf(r1); o.z = f2bf(r2); o.w = f2bf(r3);
    *(ushort4*)(hout + e) = o;
    if (WRITE_F32) { float4 f; f.x = r0; f.y = r1; f.z = r2; f.w = r3; *(float4*)(fout + e) = f; }
}

// ---------------------------------------------------------------------------
// Generic 128x128-tile MFMA GEMM for the small GEMMs.
// AMODE 1: A = bf16 row-major (ws), lda given
// AMODE 2: A = h (V,N,H) bf16 (ws), K runs over v*H+h', scaled by attn[v]
// EPI 1: dinv[row]*acc ; EPI 2: relu(acc + bias[col]) ; EPI 3: acc + bias[col]
template<int AMODE, int EPI, int OUTF32>
__global__ __launch_bounds__(256) void gemm_k(
    const void* __restrict__ Aany, long a_zs, int lda,
    const ushort* __restrict__ Bt, long b_zs, int ldb,
    void* __restrict__ Cc, long c_zs, int ldc,
    int Ktot,
    const float* __restrict__ dinv, int dinv_zs,
    const float* __restrict__ bias, int bias_zs,
    const float* __restrict__ attnp)
{
    __shared__ __align__(16) ushort As[128][40];
    __shared__ __align__(16) ushort Bs[128][40];
    const int tid = threadIdx.x;
    const int bx = blockIdx.x, by = blockIdx.y, z = blockIdx.z;
    const int m0 = by * 128, n0 = bx * 128;
    const int lane = tid & 63, w = tid >> 6, wr = w >> 1, wcq = w & 1;
    f32x4 acc[4][4] = {};
    float att0 = 0.f, att1 = 0.f, att2 = 0.f;
    if (AMODE == 2) { att0 = attnp[0]; att1 = attnp[1]; att2 = attnp[2]; }
    const ushort* Ab = (const ushort*)Aany + (long)z * (AMODE == 1 ? a_zs : 0);
    const ushort* Btz = Bt + (long)z * b_zs;

    for (int k0 = 0; k0 < Ktot; k0 += 32) {
        if (AMODE == 1) {
            #pragma unroll
            for (int p = 0; p < 2; p++) {
                int c = p * 256 + tid;
                int row = c >> 2, q = c & 3;
                *(int4*)&As[row][q * 8] = *(const int4*)(Ab + (long)(m0 + row) * lda + k0 + q * 8);
            }
        } else {
            #pragma unroll
            for (int p = 0; p < 2; p++) {
                int c = p * 256 + tid;
                int row = c >> 2, q = c & 3;
                int kk = k0 + q * 8;
                int v = kk >> 7, ko = kk & 127;
                int4 raw = *(const int4*)((const ushort*)Aany + (long)v * a_zs + (long)(m0 + row) * HH + ko);
                float sc = (v == 0) ? att0 : (v == 1 ? att1 : att2);
                __align__(16) ushort us[8];
                *(int4*)us = raw;
                #pragma unroll
                for (int e = 0; e < 8; e++) us[e] = f2bf(bf2f(us[e]) * sc);
                *(int4*)&As[row][q * 8] = *(int4*)us;
            }
        }
        #pragma unroll
        for (int p = 0; p < 2; p++) {
            int c = p * 256 + tid;
            int n = c >> 2, q = c & 3;
            *(int4*)&Bs[n][q * 8] = *(const int4*)(Btz + (long)(n0 + n) * ldb + k0 + q * 8);
        }
        __syncthreads();
        bf16x8 af[4], bfr[4];
        #pragma unroll
        for (int mi = 0; mi < 4; mi++)
            af[mi] = *(const bf16x8*)&As[wr * 64 + mi * 16 + (lane & 15)][(lane >> 4) * 8];
        #pragma unroll
        for (int ni = 0; ni < 4; ni++)
            bfr[ni] = *(const bf16x8*)&Bs[wcq * 64 + ni * 16 + (lane & 15)][(lane >> 4) * 8];
        #pragma unroll
        for (int mi = 0; mi < 4; mi++)
            #pragma unroll
            for (int ni = 0; ni < 4; ni++)
                acc[mi][ni] = __builtin_amdgcn_mfma_f32_16x16x32_bf16(af[mi], bfr[ni], acc[mi][ni], 0, 0, 0);
        __syncthreads();
    }

    #pragma unroll
    for (int mi = 0; mi < 4; mi++) {
        int rbase = m0 + wr * 64 + mi * 16 + ((lane >> 4) << 2);
        #pragma unroll
        for (int ni = 0; ni < 4; ni++) {
            int col = n0 + wcq * 64 + ni * 16 + (lane & 15);
            #pragma unroll
            for (int r = 0; r < 4; r++) {
                int grow = rbase + r;
                float vv = acc[mi][ni][r];
                if (EPI == 1) vv *= dinv[(long)z * dinv_zs + grow];
                if (EPI == 2 || EPI == 3) vv += bias[col];
                if (EPI == 2) vv = fmaxf(vv, 0.0f);
                if (OUTF32) ((float*)Cc + (long)z * c_zs)[(long)grow * ldc + col] = vv;
                else        ((ushort*)Cc + (long)z * c_zs)[(long)grow * ldc + col] = f2bf(vv);
            }
        }
    }
}

// ---------------------------------------------------------------------------
// column sums of h2 (bf16 ws) into summ[v*H+col]
__global__ __launch_bounds__(256) void colsum_k(const ushort* __restrict__ h2,
                                                float* __restrict__ summ) {
    const int rowbase = blockIdx.x * 64;
    const int z = rowbase >> 13;
    const int col = threadIdx.x & 127, half = threadIdx.x >> 7;
    float s = 0.0f;
    for (int r = half; r < 64; r += 2) s += bf2f(h2[(long)(rowbase + r) * HH + col]);
    atomicAdd(&summ[z * HH + col], s);
}

// ---------------------------------------------------------------------------
// attention: summ(sum)/N -> tanh(@Wa1+ba1)@Wa2+ba2 -> softmax over V
__global__ __launch_bounds__(256) void attn_k(const float* __restrict__ summ,
                                              const float* __restrict__ Wa1,
                                              const float* __restrict__ ba1,
                                              const float* __restrict__ Wa2,
                                              const float* __restrict__ ba2,
                                              float* __restrict__ attnws,
                                              float* __restrict__ out_attn) {
    __shared__ float sc[VV];
    const int tid = threadIdx.x;
    if (tid < VV * 64) {
        const int v = tid >> 6, a = tid & 63;
        float s = ba1[a];
        const float invN = 1.0f / (float)NN;
        #pragma unroll 4
        for (int h = 0; h < HH; h++) s += summ[v * HH + h] * invN * Wa1[h * ADIM + a];
        float p = tanhf(s) * Wa2[a];
        for (int off = 32; off; off >>= 1) p += __shfl_down(p, off);
        if (a == 0) sc[v] = p + ba2[0];
    }
    __syncthreads();
    if (tid == 0) {
        float m = fmaxf(sc[0], fmaxf(sc[1], sc[2]));
        float e0 = expf(sc[0] - m), e1 = expf(sc[1] - m), e2 = expf(sc[2] - m);
        float inv = 1.0f / (e0 + e1 + e2);
        attnws[0] = e0 * inv; attnws[1] = e1 * inv; attnws[2] = e2 * inv;
        out_attn[0] = e0 * inv; out_attn[1] = e1 * inv; out_attn[2] = e2 * inv;
    }
}

// ---------------------------------------------------------------------------
extern "C" void kernel_launch(void* const* d_in, const int* in_sizes, int n_in,
                              void* d_out, int out_size, void* d_ws, size_t ws_size,
                              hipStream_t stream) {
    const int*   adj = (const int*)d_in[0];
    const float* W1  = (const float*)d_in[1];
    const float* b1  = (const float*)d_in[2];
    const float* W2  = (const float*)d_in[3];
    const float* b2  = (const float*)d_in[4];
    const float* Wa1 = (const float*)d_in[5];
    const float* ba1 = (const float*)d_in[6];
    const float* Wa2 = (const float*)d_in[7];
    const float* ba2 = (const float*)d_in[8];
    const float* Wf1 = (const float*)d_in[9];
    const float* bf1 = (const float*)d_in[10];
    const float* Wf2 = (const float*)d_in[11];
    const float* bf2v = (const float*)d_in[12];

    float* out = (float*)d_out;
    float* out_fused = out;                                  // (N, FOUT)
    float* out_attn  = out + (long)NN * FOUT;                // (V,)
    float* out_h     = out + (long)NN * FOUT + VV;           // (V,N,H)

    char* wsb = (char*)d_ws;
    const long SZ_DINV  = (long)VV * NN * 4;                 // 98304
    const long SZ_ABITS = (long)VV * 64 * 128 * 1024;        // 25165824
    const long SZ_W1T   = (long)VV * HH * NN * 2;            // 6291456
    const long SZ_W2T   = (long)VV * HH * HH * 2;            // 98304
    const long SZ_WF1T  = 256L * 384 * 2;                    // 196608
    const long SZ_WF2T  = 128L * 256 * 2;                    // 65536
    const long SZ_VNH   = (long)VV * NN * HH * 2;            // 6291456
    const long SZ_PART  = (long)KSPLIT * VV * NN * HH * 4;   // 50331648
    const long SZ_G     = (long)NN * 256 * 2;                // 4194304
    long off = 0;
    float*  dinv  = (float*)(wsb + off);  off += SZ_DINV;
    uchar*  abits = (uchar*)(wsb + off);  off += SZ_ABITS;
    ushort* w1t   = (ushort*)(wsb + off); off += SZ_W1T;
    ushort* w2t   = (ushort*)(wsb + off); off += SZ_W2T;
    ushort* wf1t  = (ushort*)(wsb + off); off += SZ_WF1T;
    ushort* wf2t  = (ushort*)(wsb + off); off += SZ_WF2T;
    ushort* h1    = (ushort*)(wsb + off); off += SZ_VNH;
    ushort* tbuf  = (ushort*)(wsb + off); off += SZ_VNH;
    ushort* tT    = (ushort*)(wsb + off); off += SZ_VNH;
    ushort* h2    = (ushort*)(wsb + off); off += SZ_VNH;
    float*  cpart = (float*)(wsb + off);  off += SZ_PART;
    ushort* G     = (ushort*)(wsb + off); off += SZ_G;
    float*  summ  = (float*)(wsb + off);  off += 1600;       // 400 floats
    float*  attnw = summ + 384;                              // inside zeroed region

    const long VNH = (long)NN * HH;

    // 1) zero summ/attn scratch
    zero_k<<<2, 256, 0, stream>>>(summ, 400);
    // 2) bit-pack adjacency (coalesced reads, tiled bit layout) + fused dinv
    pack_k<<<(VV * NN) / 4, 256, 0, stream>>>(adj, abits, dinv);
    // 3) weight transposes (B operands staged as (Ncols x K) row-major, bf16)
    transpose_scale_k<1><<<dim3(4, 256, VV), 256, 0, stream>>>(W1, w1t, NN, HH, dinv, NN);
    transpose_scale_k<1><<<dim3(4, 4, VV), 256, 0, stream>>>(W2, w2t, HH, HH, nullptr, 0);
    transpose_scale_k<1><<<dim3(8, 12, 1), 256, 0, stream>>>(Wf1, wf1t, 384, 256, nullptr, 0);
    transpose_scale_k<1><<<dim3(4, 8, 1), 256, 0, stream>>>(Wf2, wf2t, 256, 128, nullptr, 0);
    // 4) GEMM1 partials: A(bits) @ (dinv_j*W1)
    gemm_adj_k<<<dim3(KSPLIT, 64, VV), 256, 0, stream>>>(abits, w1t, cpart);
    // 5) h1 = relu(dinv_i * sum + b1)
    reduce_k<0><<<3072, 256, 0, stream>>>(cpart, dinv, b1, h1, nullptr);
    // 6) t = dinv_k * (h1 @ W2)
    gemm_k<1, 1, 0><<<dim3(1, 64, VV), 256, 0, stream>>>(h1, VNH, HH, w2t, (long)HH * HH, HH,
                                                         tbuf, VNH, HH, HH, dinv, NN, nullptr, 0, nullptr);
    // 7) tT[v][n][k] = t[v][k][n]
    transpose_scale_k<0><<<dim3(4, 256, VV), 256, 0, stream>>>(tbuf, tT, NN, HH, nullptr, 0);
    // 8) GEMM2 partials: A(bits) @ t
    gemm_adj_k<<<dim3(KSPLIT, 64, VV), 256, 0, stream>>>(abits, tT, cpart);
    // 9) h2 = relu(dinv_i * sum + b2) -> bf16 ws + f32 out
    reduce_k<1><<<3072, 256, 0, stream>>>(cpart, dinv, b2, h2, out_h);
    // 10) column sums for attention
    colsum_k<<<(VV * NN) / 64, 256, 0, stream>>>(h2, summ);
    // 11) attention weights
    attn_k<<<1, 256, 0, stream>>>(summ, Wa1, ba1, Wa2, ba2, attnw, out_attn);
    // 12) G = relu([attn_v*h_v] @ Wf1 + bf1)   (M=8192, K=384, Ncols=256)
    gemm_k<2, 2, 0><<<dim3(2, 64, 1), 256, 0, stream>>>(h2, VNH, HH, wf1t, 0, 384,
                                                        G, 0, 256, 384, nullptr, 0, bf1, 0, attnw);
    // 13) fused = G @ Wf2 + bf2                (M=8192, K=256, Ncols=128)
    gemm_k<1, 3, 1><<<dim3(1, 64, 1), 256, 0, stream>>>(G, 0, 256, wf2t, 0, 256,
                                                        out_fused, 0, FOUT, 256, nullptr, 0, bf2v, 0, nullptr);
}

// Round 10
// 1238.734 us; speedup vs baseline: 1.2787x; 1.0225x over previous
//
#include <hip/hip_runtime.h>
#include <hip/hip_bf16.h>

// Problem constants
#define VV 3
#define NN 8192
#define HH 128
#define ADIM 64
#define FOUT 128
#define KSPLIT 4

typedef short bf16x8 __attribute__((ext_vector_type(8)));
typedef float f32x4 __attribute__((ext_vector_type(4)));
typedef unsigned char uchar;

__device__ __forceinline__ float bf2f(ushort u) {
    union { unsigned int i; float f; } x; x.i = ((unsigned int)u) << 16; return x.f;
}
__device__ __forceinline__ ushort f2bf(float f) {
    union { float f; unsigned int i; } x; x.f = f;
    unsigned int r = (x.i + 0x7FFFu + ((x.i >> 16) & 1u)) >> 16;
    return (ushort)r;
}
__device__ __forceinline__ void async_cp16(const void* g, void* l) {
    __builtin_amdgcn_global_load_lds(
        (const __attribute__((address_space(1))) void*)g,
        (__attribute__((address_space(3))) void*)l, 16, 0, 0);
}

// ---------------------------------------------------------------------------
// zero a small float region (summ + attn scratch)
__global__ void zero_k(float* p, int n) {
    int i = blockIdx.x * blockDim.x + threadIdx.x;
    if (i < n) p[i] = 0.0f;
}

// ---------------------------------------------------------------------------
// pack adjacency to 1-bit tiled layout, fully-coalesced reads (R9 validated).
__global__ __launch_bounds__(256) void pack_k(const int* __restrict__ adj,
                                              uchar* __restrict__ abits,
                                              float* __restrict__ dinv) {
    __shared__ uint rowbuf[4][256];                // per-wave 1 KB row image
    const int t = threadIdx.x, w = t >> 6, lane = t & 63;
    const long rowg = (long)blockIdx.x * 4 + w;    // z*N + n
    const int n = (int)(rowg & (NN - 1));
    const int z = (int)(rowg >> 13);
    const int mt = n >> 7, r = n & 127;
    const int* row = adj + rowg * NN;
    int cnt = 0;
    for (int it = 0; it < 32; it++) {
        const int c0 = it * 256 + lane * 4;
        const int4 v = *(const int4*)(row + c0);
        uint nib = (uint)(v.x != 0 || c0 + 0 == n)
                 | ((uint)(v.y != 0 || c0 + 1 == n) << 1)
                 | ((uint)(v.z != 0 || c0 + 2 == n) << 2)
                 | ((uint)(v.w != 0 || c0 + 3 == n) << 3);
        cnt += __popc(nib);
        uint x = nib << ((lane & 1) * 4);
        x |= __shfl_xor(x, 1);
        x <<= ((lane >> 1) & 1) * 8;
        x |= __shfl_xor(x, 2);
        x <<= ((lane >> 2) & 1) * 16;
        x |= __shfl_xor(x, 4);                     // all 8 lanes: u32 for cols base..+31
        if ((lane & 7) == 0) rowbuf[w][it * 8 + (lane >> 3)] = x;
    }
    for (int off = 32; off; off >>= 1) cnt += __shfl_down(cnt, off);
    if (lane == 0) dinv[rowg] = rsqrtf((float)cnt);
    __syncthreads();
    uint2* dstbase = (uint2*)(abits + (((long)z * 64 + mt) * 128 << 10) + r * 8);
    #pragma unroll
    for (int ph = 0; ph < 2; ph++) {
        const int kc = ph * 64 + lane;
        dstbase[(long)kc * 128] = *(const uint2*)&rowbuf[w][kc * 2];
    }
}

// ---------------------------------------------------------------------------
// all 4 weight transposes in one launch (32x32 LDS tile each).
// blocks: [0,3072) W1(+dinv scale), [3072,3120) W2, [3120,3216) Wf1, rest Wf2.
__global__ __launch_bounds__(256) void transpose_all_k(
    const float* __restrict__ W1, const float* __restrict__ W2,
    const float* __restrict__ Wf1, const float* __restrict__ Wf2,
    ushort* __restrict__ w1t, ushort* __restrict__ w2t,
    ushort* __restrict__ wf1t, ushort* __restrict__ wf2t,
    const float* __restrict__ dinvp)
{
    __shared__ ushort tile[32][33];
    const int bid = blockIdx.x, t = threadIdx.x;
    const float* in; ushort* out; const float* scale = nullptr;
    int R, C, cx, cy;
    if (bid < 3072) {
        int zz = bid >> 10, r = bid & 1023;
        cx = r & 3; cy = r >> 2; R = NN; C = HH;
        in = W1 + (long)zz * NN * HH; out = w1t + (long)zz * NN * HH;
        scale = dinvp + zz * NN;
    } else if (bid < 3120) {
        int r = bid - 3072; int zz = r >> 4; r &= 15;
        cx = r & 3; cy = r >> 2; R = HH; C = HH;
        in = W2 + (long)zz * HH * HH; out = w2t + (long)zz * HH * HH;
    } else if (bid < 3216) {
        int r = bid - 3120; cx = r & 7; cy = r >> 3; R = 384; C = 256;
        in = Wf1; out = wf1t;
    } else {
        int r = bid - 3216; cx = r & 3; cy = r >> 2; R = 256; C = 128;
        in = Wf2; out = wf2t;
    }
    const int c0 = cx * 32, r0 = cy * 32;
    #pragma unroll
    for (int p = 0; p < 4; p++) {
        int e = p * 256 + t; int row = e >> 5, col = e & 31;
        float x = in[(long)(r0 + row) * C + c0 + col];
        if (scale) x *= scale[r0 + row];
        tile[row][col] = f2bf(x);
    }
    __syncthreads();
    #pragma unroll
    for (int p = 0; p < 4; p++) {
        int e = p * 256 + t; int row = e >> 5, col = e & 31;   // row indexes C-dim now
        out[(long)(c0 + row) * R + r0 + col] = tile[col][row];
    }
}

// ---------------------------------------------------------------------------
// bf16 transpose for tbuf -> tT (mid-pipeline), per z.
__global__ void transpose_b_k(const ushort* __restrict__ in_, ushort* __restrict__ out,
                              int R, int C) {
    __shared__ ushort tile[32][33];
    const long zo = (long)blockIdx.z * R * C;
    const int c0 = blockIdx.x * 32, r0 = blockIdx.y * 32;
    const int t = threadIdx.x;
    #pragma unroll
    for (int p = 0; p < 4; p++) {
        int e = p * 256 + t; int row = e >> 5, col = e & 31;
        tile[row][col] = in_[zo + (long)(r0 + row) * C + c0 + col];
    }
    __syncthreads();
    #pragma unroll
    for (int p = 0; p < 4; p++) {
        int e = p * 256 + t; int row = e >> 5, col = e & 31;
        out[zo + (long)(c0 + row) * R + r0 + col] = tile[col][row];
    }
}

// ---------------------------------------------------------------------------
// Adjacency GEMM with 1-bit A: Cpart[ks][v] = A(bits)@Bt^T.
// 128x128 tile, BK=64, split-K=KSPLIT, 256 threads.
// NEW wave tiling: each wave owns 32 rows x 128 cols -> A-bit expansion per
// lane halves (32 elems vs 64; no cross-wave duplication of A rows).
__global__ __launch_bounds__(256, 3) void gemm_adj_k(
    const uchar* __restrict__ abits,    // tiled bits, see pack_k
    const ushort* __restrict__ Bt,      // V x 128 x N bf16 (K-contiguous)
    float* __restrict__ Cpart)          // KSPLIT x V x N x 128 f32
{
    __shared__ __align__(16) uchar As[1024];
    __shared__ __align__(16) ushort Bs[128 * 64];
    const int tid = threadIdx.x, lane = tid & 63, w = tid >> 6;
    const int ks = blockIdx.x, mt = blockIdx.y, z = blockIdx.z;
    const int m0 = mt * 128;
    const int kbeg = ks * (NN / KSPLIT);
    const uchar* Atile = abits + (((long)z * 64 + mt) * 128 << 10);
    const ushort* Bv = Bt + (long)z * 128 * NN;
    f32x4 acc[2][8] = {};

    int srow[4], slcb[4];
    #pragma unroll
    for (int p = 0; p < 4; p++) {
        int slot = (w * 4 + p) * 64 + lane;       // 0..1023, wave-contiguous
        srow[p] = slot >> 3;                       // B row (C column)
        slcb[p] = (slot & 7) ^ (srow[p] & 7);      // XOR-swizzled 16B col-block
    }

    for (int k0 = kbeg; k0 < kbeg + NN / KSPLIT; k0 += 64) {
        if (w == 0)
            async_cp16(Atile + ((long)(k0 >> 6) << 10) + lane * 16, As + lane * 16);
        #pragma unroll
        for (int p = 0; p < 4; p++) {
            const int slot = (w * 4 + p) * 64 + lane;
            async_cp16(Bv + (long)srow[p] * NN + k0 + slcb[p] * 8, Bs + slot * 8);
        }
        __syncthreads();
        const int q = lane >> 4, lr = lane & 15;
        #pragma unroll
        for (int s = 0; s < 2; s++) {
            bf16x8 bb[8];
            const int ca = s * 4 + q;
            #pragma unroll
            for (int ni = 0; ni < 8; ni++) {
                const int rr = ni * 16 + lr;
                bb[ni] = *(const bf16x8*)&Bs[rr * 64 + ((ca ^ (rr & 7)) * 8)];
            }
            #pragma unroll
            for (int mi = 0; mi < 2; mi++) {
                const int r = w * 32 + mi * 16 + lr;
                const uint b = As[r * 8 + s * 4 + q];
                union { uint4 u; bf16x8 v; } cvt;
                cvt.u.x = ((b     ) & 1u) * 0x00003F80u | ((b >> 1) & 1u) * 0x3F800000u;
                cvt.u.y = ((b >> 2) & 1u) * 0x00003F80u | ((b >> 3) & 1u) * 0x3F800000u;
                cvt.u.z = ((b >> 4) & 1u) * 0x00003F80u | ((b >> 5) & 1u) * 0x3F800000u;
                cvt.u.w = ((b >> 6) & 1u) * 0x00003F80u | ((b >> 7) & 1u) * 0x3F800000u;
                #pragma unroll
                for (int ni = 0; ni < 8; ni++)
                    acc[mi][ni] = __builtin_amdgcn_mfma_f32_16x16x32_bf16(cvt.v, bb[ni], acc[mi][ni], 0, 0, 0);
            }
        }
        __syncthreads();
    }

    float* C = Cpart + ((long)ks * VV + z) * ((long)NN * HH);
    const int lr = lane & 15;
    #pragma unroll
    for (int mi = 0; mi < 2; mi++) {
        int rbase = m0 + w * 32 + mi * 16 + ((lane >> 4) << 2);
        #pragma unroll
        for (int ni = 0; ni < 8; ni++) {
            int col = ni * 16 + lr;
            #pragma unroll
            for (int r = 0; r < 4; r++)
                C[(long)(rbase + r) * HH + col] = acc[mi][ni][r];
        }
    }
}

// ---------------------------------------------------------------------------
// reduce KSPLIT partials + epilogue: h = relu(dinv[row]*sum + bias[v][col]),
// write bf16 (ws); WRITE_F32: also write f32 to fout (the h output region).
template<int WRITE_F32>
__global__ __launch_bounds__(256) void reduce_k(const float* __restrict__ P,
                                                const float* __restrict__ dinv,
                                                const float* __restrict__ bias,
                                                ushort* __restrict__ hout,
                                                float* __restrict__ fout) {
    const long e = ((long)blockIdx.x * 256 + threadIdx.x) * 4;
    const int v = (int)(e >> 20);                  // N*H = 2^20 per view
    const int n = (int)((e >> 7) & (NN - 1));
    const int col = (int)(e & 127);
    const long S = (long)VV * NN * HH;
    const float4 s0 = *(const float4*)(P + e);
    const float4 s1 = *(const float4*)(P + S + e);
    const float4 s2 = *(const float4*)(P + 2 * S + e);
    const float4 s3 = *(const float4*)(P + 3 * S + e);
    const float d = dinv[v * NN + n];
    const float r0 = fmaxf((s0.x + s1.x + s2.x + s3.x) * d + bias[v * HH + col + 0], 0.f);
    const float r1 = fmaxf((s0.y + s1.y + s2.y + s3.y) * d + bias[v * HH + col + 1], 0.f);
    const float r2 = fmaxf((s0.z + s1.z + s2.z + s3.z) * d + bias[v * HH + col + 2], 0.f);
    const float r3 = fmaxf((s0.w + s1.w + s2.w + s3.w) * d + bias[v * HH + col + 3], 0.f);
    ushort4 o; o.x = f2bf(r0); o.y = f2bf(r1); o.z = f2bf(r2); o.w = f2bf(r3);
    *(ushort4*)(hout + e) = o;
    if (WRITE_F32) { float4 f; f.x = r0; f.y = r1; f.z = r2; f.w = r3; *(float4*)(fout + e) = f; }
}

// ---------------------------------------------------------------------------
// Generic 128x128-tile MFMA GEMM for the small GEMMs.
// AMODE 1: A = bf16 row-major (ws), lda given
// AMODE 2: A = h (V,N,H) bf16 (ws), K runs over v*H+h', scaled by attn[v]
// EPI 1: dinv[row]*acc ; EPI 2: relu(acc + bias[col]) ; EPI 3: acc + bias[col]
template<int AMODE, int EPI, int OUTF32>
__global__ __launch_bounds__(256) void gemm_k(
    const void* __restrict__ Aany, long a_zs, int lda,
    const ushort* __restrict__ Bt, long b_zs, int ldb,
    void* __restrict__ Cc, long c_zs, int ldc,
    int Ktot,
    const float* __restrict__ dinv, int dinv_zs,
    const float* __restrict__ bias, int bias_zs,
    const float* __restrict__ attnp)
{
    __shared__ __align__(16) ushort As[128][40];
    __shared__ __align__(16) ushort Bs[128][40];
    const int tid = threadIdx.x;
    const int bx = blockIdx.x, by = blockIdx.y, z = blockIdx.z;
    const int m0 = by * 128, n0 = bx * 128;
    const int lane = tid & 63, w = tid >> 6, wr = w >> 1, wcq = w & 1;
    f32x4 acc[4][4] = {};
    float att0 = 0.f, att1 = 0.f, att2 = 0.f;
    if (AMODE == 2) { att0 = attnp[0]; att1 = attnp[1]; att2 = attnp[2]; }
    const ushort* Ab = (const ushort*)Aany + (long)z * (AMODE == 1 ? a_zs : 0);
    const ushort* Btz = Bt + (long)z * b_zs;

    for (int k0 = 0; k0 < Ktot; k0 += 32) {
        if (AMODE == 1) {
            #pragma unroll
            for (int p = 0; p < 2; p++) {
                int c = p * 256 + tid;
                int row = c >> 2, q = c & 3;
                *(int4*)&As[row][q * 8] = *(const int4*)(Ab + (long)(m0 + row) * lda + k0 + q * 8);
            }
        } else {
            #pragma unroll
            for (int p = 0; p < 2; p++) {
                int c = p * 256 + tid;
                int row = c >> 2, q = c & 3;
                int kk = k0 + q * 8;
                int v = kk >> 7, ko = kk & 127;
                int4 raw = *(const int4*)((const ushort*)Aany + (long)v * a_zs + (long)(m0 + row) * HH + ko);
                float sc = (v == 0) ? att0 : (v == 1 ? att1 : att2);
                __align__(16) ushort us[8];
                *(int4*)us = raw;
                #pragma unroll
                for (int e = 0; e < 8; e++) us[e] = f2bf(bf2f(us[e]) * sc);
                *(int4*)&As[row][q * 8] = *(int4*)us;
            }
        }
        #pragma unroll
        for (int p = 0; p < 2; p++) {
            int c = p * 256 + tid;
            int n = c >> 2, q = c & 3;
            *(int4*)&Bs[n][q * 8] = *(const int4*)(Btz + (long)(n0 + n) * ldb + k0 + q * 8);
        }
        __syncthreads();
        bf16x8 af[4], bfr[4];
        #pragma unroll
        for (int mi = 0; mi < 4; mi++)
            af[mi] = *(const bf16x8*)&As[wr * 64 + mi * 16 + (lane & 15)][(lane >> 4) * 8];
        #pragma unroll
        for (int ni = 0; ni < 4; ni++)
            bfr[ni] = *(const bf16x8*)&Bs[wcq * 64 + ni * 16 + (lane & 15)][(lane >> 4) * 8];
        #pragma unroll
        for (int mi = 0; mi < 4; mi++)
            #pragma unroll
            for (int ni = 0; ni < 4; ni++)
                acc[mi][ni] = __builtin_amdgcn_mfma_f32_16x16x32_bf16(af[mi], bfr[ni], acc[mi][ni], 0, 0, 0);
        __syncthreads();
    }

    #pragma unroll
    for (int mi = 0; mi < 4; mi++) {
        int rbase = m0 + wr * 64 + mi * 16 + ((lane >> 4) << 2);
        #pragma unroll
        for (int ni = 0; ni < 4; ni++) {
            int col = n0 + wcq * 64 + ni * 16 + (lane & 15);
            #pragma unroll
            for (int r = 0; r < 4; r++) {
                int grow = rbase + r;
                float vv = acc[mi][ni][r];
                if (EPI == 1) vv *= dinv[(long)z * dinv_zs + grow];
                if (EPI == 2 || EPI == 3) vv += bias[col];
                if (EPI == 2) vv = fmaxf(vv, 0.0f);
                if (OUTF32) ((float*)Cc + (long)z * c_zs)[(long)grow * ldc + col] = vv;
                else        ((ushort*)Cc + (long)z * c_zs)[(long)grow * ldc + col] = f2bf(vv);
            }
        }
    }
}

// ---------------------------------------------------------------------------
// column sums of h2 (bf16 ws) into summ[v*H+col]
__global__ __launch_bounds__(256) void colsum_k(const ushort* __restrict__ h2,
                                                float* __restrict__ summ) {
    const int rowbase = blockIdx.x * 64;
    const int z = rowbase >> 13;
    const int col = threadIdx.x & 127, half = threadIdx.x >> 7;
    float s = 0.0f;
    for (int r = half; r < 64; r += 2) s += bf2f(h2[(long)(rowbase + r) * HH + col]);
    atomicAdd(&summ[z * HH + col], s);
}

// ---------------------------------------------------------------------------
// attention: summ(sum)/N -> tanh(@Wa1+ba1)@Wa2+ba2 -> softmax over V
__global__ __launch_bounds__(256) void attn_k(const float* __restrict__ summ,
                                              const float* __restrict__ Wa1,
                                              const float* __restrict__ ba1,
                                              const float* __restrict__ Wa2,
                                              const float* __restrict__ ba2,
                                              float* __restrict__ attnws,
                                              float* __restrict__ out_attn) {
    __shared__ float sc[VV];
    const int tid = threadIdx.x;
    if (tid < VV * 64) {
        const int v = tid >> 6, a = tid & 63;
        float s = ba1[a];
        const float invN = 1.0f / (float)NN;
        #pragma unroll 4
        for (int h = 0; h < HH; h++) s += summ[v * HH + h] * invN * Wa1[h * ADIM + a];
        float p = tanhf(s) * Wa2[a];
        for (int off = 32; off; off >>= 1) p += __shfl_down(p, off);
        if (a == 0) sc[v] = p + ba2[0];
    }
    __syncthreads();
    if (tid == 0) {
        float m = fmaxf(sc[0], fmaxf(sc[1], sc[2]));
        float e0 = expf(sc[0] - m), e1 = expf(sc[1] - m), e2 = expf(sc[2] - m);
        float inv = 1.0f / (e0 + e1 + e2);
        attnws[0] = e0 * inv; attnws[1] = e1 * inv; attnws[2] = e2 * inv;
        out_attn[0] = e0 * inv; out_attn[1] = e1 * inv; out_attn[2] = e2 * inv;
    }
}

// ---------------------------------------------------------------------------
extern "C" void kernel_launch(void* const* d_in, const int* in_sizes, int n_in,
                              void* d_out, int out_size, void* d_ws, size_t ws_size,
                              hipStream_t stream) {
    const int*   adj = (const int*)d_in[0];
    const float* W1  = (const float*)d_in[1];
    const float* b1  = (const float*)d_in[2];
    const float* W2  = (const float*)d_in[3];
    const float* b2  = (const float*)d_in[4];
    const float* Wa1 = (const float*)d_in[5];
    const float* ba1 = (const float*)d_in[6];
    const float* Wa2 = (const float*)d_in[7];
    const float* ba2 = (const float*)d_in[8];
    const float* Wf1 = (const float*)d_in[9];
    const float* bf1 = (const float*)d_in[10];
    const float* Wf2 = (const float*)d_in[11];
    const float* bf2v = (const float*)d_in[12];

    float* out = (float*)d_out;
    float* out_fused = out;                                  // (N, FOUT)
    float* out_attn  = out + (long)NN * FOUT;                // (V,)
    float* out_h     = out + (long)NN * FOUT + VV;           // (V,N,H)

    char* wsb = (char*)d_ws;
    const long SZ_DINV  = (long)VV * NN * 4;                 // 98304
    const long SZ_ABITS = (long)VV * 64 * 128 * 1024;        // 25165824
    const long SZ_W1T   = (long)VV * HH * NN * 2;            // 6291456
    const long SZ_W2T   = (long)VV * HH * HH * 2;            // 98304
    const long SZ_WF1T  = 256L * 384 * 2;                    // 196608
    const long SZ_WF2T  = 128L * 256 * 2;                    // 65536
    const long SZ_VNH   = (long)VV * NN * HH * 2;            // 6291456
    const long SZ_PART  = (long)KSPLIT * VV * NN * HH * 4;   // 50331648
    const long SZ_G     = (long)NN * 256 * 2;                // 4194304
    long off = 0;
    float*  dinv  = (float*)(wsb + off);  off += SZ_DINV;
    uchar*  abits = (uchar*)(wsb + off);  off += SZ_ABITS;
    ushort* w1t   = (ushort*)(wsb + off); off += SZ_W1T;
    ushort* w2t   = (ushort*)(wsb + off); off += SZ_W2T;
    ushort* wf1t  = (ushort*)(wsb + off); off += SZ_WF1T;
    ushort* wf2t  = (ushort*)(wsb + off); off += SZ_WF2T;
    ushort* h1    = (ushort*)(wsb + off); off += SZ_VNH;
    ushort* tbuf  = (ushort*)(wsb + off); off += SZ_VNH;
    ushort* tT    = (ushort*)(wsb + off); off += SZ_VNH;
    ushort* h2    = (ushort*)(wsb + off); off += SZ_VNH;
    float*  cpart = (float*)(wsb + off);  off += SZ_PART;
    ushort* G     = (ushort*)(wsb + off); off += SZ_G;
    float*  summ  = (float*)(wsb + off);  off += 1600;       // 400 floats
    float*  attnw = summ + 384;                              // inside zeroed region

    const long VNH = (long)NN * HH;

    // 1) zero summ/attn scratch
    zero_k<<<2, 256, 0, stream>>>(summ, 400);
    // 2) bit-pack adjacency (coalesced reads, tiled bit layout) + fused dinv
    pack_k<<<(VV * NN) / 4, 256, 0, stream>>>(adj, abits, dinv);
    // 3) all weight transposes in one launch (W1 scaled by dinv)
    transpose_all_k<<<3248, 256, 0, stream>>>(W1, W2, Wf1, Wf2, w1t, w2t, wf1t, wf2t, dinv);
    // 4) GEMM1 partials: A(bits) @ (dinv_j*W1)
    gemm_adj_k<<<dim3(KSPLIT, 64, VV), 256, 0, stream>>>(abits, w1t, cpart);
    // 5) h1 = relu(dinv_i * sum + b1)
    reduce_k<0><<<3072, 256, 0, stream>>>(cpart, dinv, b1, h1, nullptr);
    // 6) t = dinv_k * (h1 @ W2)
    gemm_k<1, 1, 0><<<dim3(1, 64, VV), 256, 0, stream>>>(h1, VNH, HH, w2t, (long)HH * HH, HH,
                                                         tbuf, VNH, HH, HH, dinv, NN, nullptr, 0, nullptr);
    // 7) tT[v][n][k] = t[v][k][n]
    transpose_b_k<<<dim3(4, 256, VV), 256, 0, stream>>>(tbuf, tT, NN, HH);
    // 8) GEMM2 partials: A(bits) @ t
    gemm_adj_k<<<dim3(KSPLIT, 64, VV), 256, 0, stream>>>(abits, tT, cpart);
    // 9) h2 = relu(dinv_i * sum + b2) -> bf16 ws + f32 out
    reduce_k<1><<<3072, 256, 0, stream>>>(cpart, dinv, b2, h2, out_h);
    // 10) column sums for attention
    colsum_k<<<(VV * NN) / 64, 256, 0, stream>>>(h2, summ);
    // 11) attention weights
    attn_k<<<1, 256, 0, stream>>>(summ, Wa1, ba1, Wa2, ba2, attnw, out_attn);
    // 12) G = relu([attn_v*h_v] @ Wf1 + bf1)   (M=8192, K=384, Ncols=256)
    gemm_k<2, 2, 0><<<dim3(2, 64, 1), 256, 0, stream>>>(h2, VNH, HH, wf1t, 0, 384,
                                                        G, 0, 256, 384, nullptr, 0, bf1, 0, attnw);
    // 13) fused = G @ Wf2 + bf2                (M=8192, K=256, Ncols=128)
    gemm_k<1, 3, 1><<<dim3(1, 64, 1), 256, 0, stream>>>(G, 0, 256, wf2t, 0, 256,
                                                        out_fused, 0, FOUT, 256, nullptr, 0, bf2v, 0, nullptr);
}